// Round 12
// baseline (68.487 us; speedup 1.0000x reference)
//
#include <hip/hip_runtime.h>
#include <math.h>

// FinalGNN: b=16, n=256, feature=64. All row-major [4096][64] work tensors.
#define OFF_H      0
#define OFF_AI     262144
#define OFF_AJ     524288
#define OFF_SAI    786432
#define OFF_QAI    790528
#define OFF_SAJ    794624
#define OFF_QAJ    798720
#define OFF_SQH    802816
#define OFF_HRES   806912
// total 1,069,056 floats = 4.3 MB

__device__ __forceinline__ float elu_f(float x) { return x > 0.f ? x : expm1f(x); }

// K1: h = elu(x@proj_w+proj_b); a_i = h@s_w1[:64]+s_b1; a_j = h@s_w1[64:];
// row scalars via butterfly. 512 blocks x 256 thr; s_w1 staged in LDS (32KB).
__global__ __launch_bounds__(256) void k1_embed(
    const float* __restrict__ x,
    const float* __restrict__ proj_w, const float* __restrict__ proj_b,
    const float* __restrict__ s_w1, const float* __restrict__ s_b1,
    float* __restrict__ h, float* __restrict__ a_i, float* __restrict__ a_j,
    float* __restrict__ sa_i, float* __restrict__ qa_i,
    float* __restrict__ sa_j, float* __restrict__ qa_j,
    float* __restrict__ sqh)
{
    __shared__ float w_sh[8192];   // s_w1 [128][64]
    int tid = threadIdx.x;
    #pragma unroll
    for (int r = 0; r < 8; ++r)
        *(float4*)&w_sh[(r*256 + tid)*4] = *(const float4*)&s_w1[(r*256 + tid)*4];
    __syncthreads();

    int lane = tid & 63;
    int wave = tid >> 6;
    int row0 = blockIdx.x * 8;

    float pw0 = proj_w[lane], pw1 = proj_w[64+lane], pw2 = proj_w[128+lane],
          pw3 = proj_w[192+lane], pb = proj_b[lane], b1 = s_b1[lane];

    #pragma unroll
    for (int r = 0; r < 2; ++r) {
        int row = row0 + wave*2 + r;          // b*256 + i
        float4 xv = *(const float4*)&x[row*4];
        float hv = elu_f(xv.x*pw0 + xv.y*pw1 + xv.z*pw2 + xv.w*pw3 + pb);

        float ai = b1, aj = 0.f;
        #pragma unroll 8
        for (int e = 0; e < 64; ++e) {
            float he = __shfl(hv, e);
            ai = fmaf(he, w_sh[e*64 + lane], ai);
            aj = fmaf(he, w_sh[(64+e)*64 + lane], aj);
        }
        h[row*64 + lane]   = hv;
        a_i[row*64 + lane] = ai;
        a_j[row*64 + lane] = aj;

        float v1 = ai, v2 = ai*ai, v3 = aj, v4 = aj*aj, v5 = hv*hv;
        #pragma unroll
        for (int off = 32; off > 0; off >>= 1) {
            v1 += __shfl_xor(v1, off);
            v2 += __shfl_xor(v2, off);
            v3 += __shfl_xor(v3, off);
            v4 += __shfl_xor(v4, off);
            v5 += __shfl_xor(v5, off);
        }
        if (lane == 0) {
            sa_i[row] = v1; qa_i[row] = v2;
            sa_j[row] = v3; qa_j[row] = v4;
            sqh[row]  = v5;
        }
    }
}

// K2: fused pair kernel, minimal memory-instruction count.
// 1024 blocks x 256 threads. block = (b, 4-i tile), thread = j.
// h_j row burst (16 x float4, dies) -> gh; a_j row burst (16 x float4, KEPT) -> ga;
// stats via scalar decomposition; pass2 from registers; adj; float4 aggregation;
// gnn_w via LDS pool (reused, FULL 4096 floats); fused gnn GEMV + residual + elu.
__global__ __launch_bounds__(256) void k2_pair(
    const float* __restrict__ a_i, const float* __restrict__ a_jr,
    const float* __restrict__ h,
    const float* __restrict__ sa_i, const float* __restrict__ qa_i,
    const float* __restrict__ sa_j, const float* __restrict__ qa_j,
    const float* __restrict__ sqh,
    const float* __restrict__ ln_g, const float* __restrict__ ln_b,
    const float* __restrict__ s_w2, const float* __restrict__ s_b2,
    const float* __restrict__ gnn_w,
    float* __restrict__ h_res)
{
    int bi0 = blockIdx.x * 4;          // first row (b*256 + i0)
    int b   = bi0 >> 8;
    int j   = threadIdx.x;
    int gj  = b*256 + j;

    __shared__ float aiT[64][4], hiT[64][4];   // [d][i]
    __shared__ float gbw[64][4];               // {ln_g, ln_b, s_w2, 0}
    __shared__ float sai_s[4], qai_s[4], sqi_s[4];
    __shared__ float adj_sh[256][4];           // [j][i]
    __shared__ float pool[4096];               // part_sh [16][4][64], then gnn_sh
    __shared__ float hagg_sh[4][64];

    {
        int i = j >> 6, d = j & 63;
        aiT[d][i] = a_i[(bi0+i)*64 + d];
        hiT[d][i] = h[(bi0+i)*64 + d];
    }
    if (j < 64) {
        gbw[j][0] = ln_g[j]; gbw[j][1] = ln_b[j]; gbw[j][2] = s_w2[j]; gbw[j][3] = 0.f;
    }
    if (j < 4) {
        sai_s[j] = sa_i[bi0+j]; qai_s[j] = qa_i[bi0+j]; sqi_s[j] = sqh[bi0+j];
    }
    float saj = sa_j[gj], qaj = qa_j[gj], sqj = sqh[gj];
    float b2  = s_b2[0];
    __syncthreads();

    // ---- phase A: gh = h_i . h_j from h_j row burst (registers die after) ----
    float gh4[4] = {0.f,0.f,0.f,0.f};
    {
        float4 hj[16];
        const float* hr = h + gj*64;
        #pragma unroll
        for (int g = 0; g < 16; ++g) hj[g] = *(const float4*)&hr[g*4];
        #pragma unroll
        for (int g = 0; g < 16; ++g) {
            float4 v = hj[g];
            int d0 = g*4;
            float4 H0 = *(const float4*)&hiT[d0+0][0];
            gh4[0]=fmaf(H0.x,v.x,gh4[0]); gh4[1]=fmaf(H0.y,v.x,gh4[1]);
            gh4[2]=fmaf(H0.z,v.x,gh4[2]); gh4[3]=fmaf(H0.w,v.x,gh4[3]);
            float4 H1 = *(const float4*)&hiT[d0+1][0];
            gh4[0]=fmaf(H1.x,v.y,gh4[0]); gh4[1]=fmaf(H1.y,v.y,gh4[1]);
            gh4[2]=fmaf(H1.z,v.y,gh4[2]); gh4[3]=fmaf(H1.w,v.y,gh4[3]);
            float4 H2 = *(const float4*)&hiT[d0+2][0];
            gh4[0]=fmaf(H2.x,v.z,gh4[0]); gh4[1]=fmaf(H2.y,v.z,gh4[1]);
            gh4[2]=fmaf(H2.z,v.z,gh4[2]); gh4[3]=fmaf(H2.w,v.z,gh4[3]);
            float4 H3 = *(const float4*)&hiT[d0+3][0];
            gh4[0]=fmaf(H3.x,v.w,gh4[0]); gh4[1]=fmaf(H3.y,v.w,gh4[1]);
            gh4[2]=fmaf(H3.z,v.w,gh4[2]); gh4[3]=fmaf(H3.w,v.w,gh4[3]);
        }
    }

    // ---- phase B: a_j row burst, KEPT live through stats + pass 2 ----
    float4 aj[16];
    {
        const float* ar = a_jr + gj*64;
        #pragma unroll
        for (int g = 0; g < 16; ++g) aj[g] = *(const float4*)&ar[g*4];
    }
    float ga4[4] = {0.f,0.f,0.f,0.f};
    #pragma unroll
    for (int g = 0; g < 16; ++g) {
        float4 v = aj[g];
        int d0 = g*4;
        float4 A0 = *(const float4*)&aiT[d0+0][0];
        ga4[0]=fmaf(A0.x,v.x,ga4[0]); ga4[1]=fmaf(A0.y,v.x,ga4[1]);
        ga4[2]=fmaf(A0.z,v.x,ga4[2]); ga4[3]=fmaf(A0.w,v.x,ga4[3]);
        float4 A1 = *(const float4*)&aiT[d0+1][0];
        ga4[0]=fmaf(A1.x,v.y,ga4[0]); ga4[1]=fmaf(A1.y,v.y,ga4[1]);
        ga4[2]=fmaf(A1.z,v.y,ga4[2]); ga4[3]=fmaf(A1.w,v.y,ga4[3]);
        float4 A2 = *(const float4*)&aiT[d0+2][0];
        ga4[0]=fmaf(A2.x,v.z,ga4[0]); ga4[1]=fmaf(A2.y,v.z,ga4[1]);
        ga4[2]=fmaf(A2.z,v.z,ga4[2]); ga4[3]=fmaf(A2.w,v.z,ga4[3]);
        float4 A3 = *(const float4*)&aiT[d0+3][0];
        ga4[0]=fmaf(A3.x,v.w,ga4[0]); ga4[1]=fmaf(A3.y,v.w,ga4[1]);
        ga4[2]=fmaf(A3.z,v.w,ga4[2]); ga4[3]=fmaf(A3.w,v.w,ga4[3]);
    }

    // ---- LN stats from scalar decomposition ----
    float rs4[4], nr4[4], d24[4];
    #pragma unroll
    for (int i = 0; i < 4; ++i) {
        float mu  = (sai_s[i] + saj) * (1.f/64.f);
        float pss = qai_s[i] + qaj + 2.f*ga4[i];
        float var = pss * (1.f/64.f) - mu*mu;
        rs4[i] = rsqrtf(var + 1e-5f);
        nr4[i] = -mu * rs4[i];
        d24[i] = fmaxf(sqi_s[i] + sqj - 2.f*gh4[i], 0.f);
    }

    // ---- pass 2: LN -> relu -> dot(w2), a_j from registers ----
    float acc[4] = {0.f,0.f,0.f,0.f};
    #pragma unroll
    for (int g = 0; g < 16; ++g) {
        float4 v = aj[g];
        float c[4] = {v.x, v.y, v.z, v.w};
        int d0 = g*4;
        #pragma unroll
        for (int u = 0; u < 4; ++u) {
            int d = d0 + u;
            float ajd = c[u];
            float4 A = *(const float4*)&aiT[d][0];
            float4 G = *(const float4*)&gbw[d][0];
            float t0 = fmaxf(fmaf(fmaf(A.x + ajd, rs4[0], nr4[0]), G.x, G.y), 0.f);
            acc[0] = fmaf(t0, G.z, acc[0]);
            float t1 = fmaxf(fmaf(fmaf(A.y + ajd, rs4[1], nr4[1]), G.x, G.y), 0.f);
            acc[1] = fmaf(t1, G.z, acc[1]);
            float t2 = fmaxf(fmaf(fmaf(A.z + ajd, rs4[2], nr4[2]), G.x, G.y), 0.f);
            acc[2] = fmaf(t2, G.z, acc[2]);
            float t3 = fmaxf(fmaf(fmaf(A.w + ajd, rs4[3], nr4[3]), G.x, G.y), 0.f);
            acc[3] = fmaf(t3, G.z, acc[3]);
        }
    }

    // ---- sigma, adj ----
    {
        float4 av;
        float sp0 = acc[0] + b2;
        float sg0 = fmaxf(sp0, 0.f) + log1pf(expf(-fabsf(sp0)));
        av.x = expf(-d24[0] / (2.f*sg0*sg0 + 1e-6f));
        float sp1 = acc[1] + b2;
        float sg1 = fmaxf(sp1, 0.f) + log1pf(expf(-fabsf(sp1)));
        av.y = expf(-d24[1] / (2.f*sg1*sg1 + 1e-6f));
        float sp2 = acc[2] + b2;
        float sg2 = fmaxf(sp2, 0.f) + log1pf(expf(-fabsf(sp2)));
        av.z = expf(-d24[2] / (2.f*sg2*sg2 + 1e-6f));
        float sp3 = acc[3] + b2;
        float sg3 = fmaxf(sp3, 0.f) + log1pf(expf(-fabsf(sp3)));
        av.w = expf(-d24[3] / (2.f*sg3*sg3 + 1e-6f));
        *(float4*)&adj_sh[j][0] = av;
    }
    __syncthreads();

    // ---- aggregation: hagg[i][d] = sum_j adj[i][j] * h[b,j,d], float4 loads ----
    {
        int dq = j & 15, q = j >> 4;          // d-quad, j-group (16 j's each)
        const float* hb = h + b*256*64;
        float4 p0 = {0.f,0.f,0.f,0.f}, p1 = p0, p2 = p0, p3 = p0;
        #pragma unroll
        for (int k = 0; k < 16; ++k) {
            int jj = q*16 + k;
            float4 hv = *(const float4*)&hb[jj*64 + dq*4];
            float4 a4 = *(const float4*)&adj_sh[jj][0];
            p0.x=fmaf(a4.x,hv.x,p0.x); p0.y=fmaf(a4.x,hv.y,p0.y);
            p0.z=fmaf(a4.x,hv.z,p0.z); p0.w=fmaf(a4.x,hv.w,p0.w);
            p1.x=fmaf(a4.y,hv.x,p1.x); p1.y=fmaf(a4.y,hv.y,p1.y);
            p1.z=fmaf(a4.y,hv.z,p1.z); p1.w=fmaf(a4.y,hv.w,p1.w);
            p2.x=fmaf(a4.z,hv.x,p2.x); p2.y=fmaf(a4.z,hv.y,p2.y);
            p2.z=fmaf(a4.z,hv.z,p2.z); p2.w=fmaf(a4.z,hv.w,p2.w);
            p3.x=fmaf(a4.w,hv.x,p3.x); p3.y=fmaf(a4.w,hv.y,p3.y);
            p3.z=fmaf(a4.w,hv.z,p3.z); p3.w=fmaf(a4.w,hv.w,p3.w);
        }
        // pool as part_sh[16][4][64]
        *(float4*)&pool[(q*4 + 0)*64 + dq*4] = p0;
        *(float4*)&pool[(q*4 + 1)*64 + dq*4] = p1;
        *(float4*)&pool[(q*4 + 2)*64 + dq*4] = p2;
        *(float4*)&pool[(q*4 + 3)*64 + dq*4] = p3;
    }
    __syncthreads();

    float hagg_mine;
    {
        int i = j >> 6, d = j & 63;
        float s = 0.f;
        #pragma unroll
        for (int q2 = 0; q2 < 16; ++q2)
            s += pool[(q2*4 + i)*64 + d];
        hagg_mine = s;
    }
    __syncthreads();                 // all pool reads done before overwrite
    {
        int i = j >> 6, d = j & 63;
        hagg_sh[i][d] = hagg_mine;
    }

    // reuse pool as gnn_sh[4096]: FULL gnn_w, 4 x float4 per thread, coalesced
    #pragma unroll
    for (int r = 0; r < 4; ++r)
        *(float4*)&pool[(r*256 + j)*4] = *(const float4*)&gnn_w[(r*256 + j)*4];
    __syncthreads();

    // ---- fused gnn: h_res = elu(hagg @ gnn_w + h) ----
    {
        int i = j >> 6, lane = j & 63;
        float accg = 0.f;
        #pragma unroll 8
        for (int e = 0; e < 64; ++e)
            accg = fmaf(hagg_sh[i][e], pool[e*64 + lane], accg);
        h_res[(bi0+i)*64 + lane] = elu_f(accg + hiT[lane][i]);
    }
}

// K4: pooled = [mean_i, max_i]; classifier.  16 blocks x 256 threads.
__global__ __launch_bounds__(256) void k4_pool_cls(
    const float* __restrict__ h_res,
    const float* __restrict__ c_w1, const float* __restrict__ c_b1,
    const float* __restrict__ bn_g, const float* __restrict__ bn_b,
    const float* __restrict__ bn_mean, const float* __restrict__ bn_var,
    const float* __restrict__ c_w2, const float* __restrict__ c_b2,
    float* __restrict__ out)
{
    int b = blockIdx.x;
    int tid = threadIdx.x;
    int d = tid & 63, q = tid >> 6;
    const float* hb = h_res + b*256*64;

    float sum = 0.f, mx = -INFINITY;
    #pragma unroll 8
    for (int k = 0; k < 64; ++k) {
        float v = hb[(q*64+k)*64 + d];
        sum += v; mx = fmaxf(mx, v);
    }
    __shared__ float sum_sh[256], max_sh[256];
    __shared__ float pm_sh[64], px_sh[64];
    sum_sh[tid] = sum; max_sh[tid] = mx;
    __syncthreads();
    if (tid < 64) {
        float tsum = sum_sh[tid] + sum_sh[64+tid] + sum_sh[128+tid] + sum_sh[192+tid];
        float tmax = fmaxf(fmaxf(max_sh[tid], max_sh[64+tid]),
                           fmaxf(max_sh[128+tid], max_sh[192+tid]));
        pm_sh[tid] = tsum * (1.f/256.f);
        px_sh[tid] = tmax;
    }
    __syncthreads();
    if (tid < 64) {
        float acc = c_b1[tid];
        #pragma unroll
        for (int e = 0; e < 64; ++e) {
            acc += pm_sh[e] * c_w1[e*64 + tid];
            acc += px_sh[e] * c_w1[(64+e)*64 + tid];
        }
        float z = (acc - bn_mean[tid]) * rsqrtf(bn_var[tid] + 1e-5f) * bn_g[tid] + bn_b[tid];
        z = elu_f(z);
        float c0 = z * c_w2[tid*2 + 0];
        float c1 = z * c_w2[tid*2 + 1];
        for (int off = 32; off > 0; off >>= 1) {
            c0 += __shfl_down(c0, off);
            c1 += __shfl_down(c1, off);
        }
        if (tid == 0) {
            out[b*2 + 0] = c0 + c_b2[0];
            out[b*2 + 1] = c1 + c_b2[1];
        }
    }
}

extern "C" void kernel_launch(void* const* d_in, const int* in_sizes, int n_in,
                              void* d_out, int out_size, void* d_ws, size_t ws_size,
                              hipStream_t stream) {
    const float* x       = (const float*)d_in[0];
    const float* proj_w  = (const float*)d_in[1];
    const float* proj_b  = (const float*)d_in[2];
    const float* s_w1    = (const float*)d_in[3];
    const float* s_b1    = (const float*)d_in[4];
    const float* ln_g    = (const float*)d_in[5];
    const float* ln_b    = (const float*)d_in[6];
    const float* s_w2    = (const float*)d_in[7];
    const float* s_b2    = (const float*)d_in[8];
    const float* gnn_w   = (const float*)d_in[9];
    const float* c_w1    = (const float*)d_in[10];
    const float* c_b1    = (const float*)d_in[11];
    const float* bn_g    = (const float*)d_in[12];
    const float* bn_b    = (const float*)d_in[13];
    const float* bn_mean = (const float*)d_in[14];
    const float* bn_var  = (const float*)d_in[15];
    const float* c_w2    = (const float*)d_in[16];
    const float* c_b2    = (const float*)d_in[17];

    float* w = (float*)d_ws;
    float* h     = w + OFF_H;
    float* a_i   = w + OFF_AI;
    float* a_j   = w + OFF_AJ;
    float* sa_i  = w + OFF_SAI;
    float* qa_i  = w + OFF_QAI;
    float* sa_j  = w + OFF_SAJ;
    float* qa_j  = w + OFF_QAJ;
    float* sqh   = w + OFF_SQH;
    float* h_res = w + OFF_HRES;
    float* out   = (float*)d_out;

    k1_embed<<<512, 256, 0, stream>>>(x, proj_w, proj_b, s_w1, s_b1,
                                      h, a_i, a_j,
                                      sa_i, qa_i, sa_j, qa_j, sqh);
    k2_pair<<<1024, 256, 0, stream>>>(a_i, a_j, h,
                                      sa_i, qa_i, sa_j, qa_j, sqh,
                                      ln_g, ln_b, s_w2, s_b2, gnn_w, h_res);
    k4_pool_cls<<<16, 256, 0, stream>>>(h_res, c_w1, c_b1, bn_g, bn_b,
                                        bn_mean, bn_var, c_w2, c_b2, out);
}

// Round 13
// 57.100 us; speedup vs baseline: 1.1994x; 1.1994x over previous
//
#include <hip/hip_runtime.h>
#include <math.h>

// FinalGNN: b=16, n=256, feature=64
// ws layout (floats):
#define OFF_H      0                    // h     [4096][64]
#define OFF_AI     262144               // a_i   [4096][64]  (includes s_b1)
#define OFF_AJT    524288               // a_jT  [16][64][256]
#define OFF_SAI    786432               // per-row scalars, 4096 each
#define OFF_QAI    790528
#define OFF_SAJ    794624
#define OFF_QAJ    798720
#define OFF_SQH    802816
#define OFF_GA     806912               // ga [4096][256]
#define OFF_GH     1855488              // gh [4096][256]
#define OFF_HAGG4  2904064              // hagg4 [4][4096][64]
#define OFF_HRES   3952640              // h_res [4096][64]
#define OFF_BF     4214784              // 3 bf16 arrays (shorts) follow

typedef __attribute__((ext_vector_type(8))) short bf16x8;
typedef __attribute__((ext_vector_type(4))) float f32x4;

__device__ __forceinline__ float elu_f(float x) { return x > 0.f ? x : expm1f(x); }

__device__ __forceinline__ short f2bf(float f) {
    unsigned u = __float_as_uint(f);
    unsigned r = (u + 0x7FFF + ((u >> 16) & 1)) >> 16;   // RNE
    return (short)r;
}

// K1 (validated R10): h, a_i, a_jT, bf16 copies, row scalars. 512 blocks x 256.
__global__ __launch_bounds__(256) void k1_embed(
    const float* __restrict__ x,
    const float* __restrict__ proj_w, const float* __restrict__ proj_b,
    const float* __restrict__ s_w1, const float* __restrict__ s_b1,
    float* __restrict__ h, float* __restrict__ a_i, float* __restrict__ a_jT,
    short* __restrict__ ai_bf, short* __restrict__ aj_bf, short* __restrict__ h_bf,
    float* __restrict__ sa_i, float* __restrict__ qa_i,
    float* __restrict__ sa_j, float* __restrict__ qa_j,
    float* __restrict__ sqh)
{
    __shared__ float w_sh[8192];   // s_w1 [128][64]
    int tid = threadIdx.x;
    #pragma unroll
    for (int r = 0; r < 8; ++r)
        *(float4*)&w_sh[(r*256 + tid)*4] = *(const float4*)&s_w1[(r*256 + tid)*4];
    __syncthreads();

    int lane = tid & 63;
    int wave = tid >> 6;
    int row0 = blockIdx.x * 8;

    float pw0 = proj_w[lane], pw1 = proj_w[64+lane], pw2 = proj_w[128+lane],
          pw3 = proj_w[192+lane], pb = proj_b[lane], b1 = s_b1[lane];

    #pragma unroll
    for (int r = 0; r < 2; ++r) {
        int row = row0 + wave*2 + r;          // b*256 + i
        int b = row >> 8, i = row & 255;
        float4 xv = *(const float4*)&x[row*4];
        float hv = elu_f(xv.x*pw0 + xv.y*pw1 + xv.z*pw2 + xv.w*pw3 + pb);

        float ai = b1, aj = 0.f;
        #pragma unroll 8
        for (int e = 0; e < 64; ++e) {
            float he = __shfl(hv, e);
            ai = fmaf(he, w_sh[e*64 + lane], ai);
            aj = fmaf(he, w_sh[(64+e)*64 + lane], aj);
        }
        h[row*64 + lane]   = hv;
        a_i[row*64 + lane] = ai;
        a_jT[b*64*256 + lane*256 + i] = aj;
        ai_bf[row*64 + lane] = f2bf(ai);
        aj_bf[row*64 + lane] = f2bf(aj);
        h_bf [row*64 + lane] = f2bf(hv);

        float v1 = ai, v2 = ai*ai, v3 = aj, v4 = aj*aj, v5 = hv*hv;
        #pragma unroll
        for (int off = 32; off > 0; off >>= 1) {
            v1 += __shfl_xor(v1, off);
            v2 += __shfl_xor(v2, off);
            v3 += __shfl_xor(v3, off);
            v4 += __shfl_xor(v4, off);
            v5 += __shfl_xor(v5, off);
        }
        if (lane == 0) {
            sa_i[row] = v1; qa_i[row] = v2;
            sa_j[row] = v3; qa_j[row] = v4;
            sqh[row]  = v5;
        }
    }
}

// KGRAM (validated R10): ga = Ai.Aj^T, gh = H.H^T via mfma_f32_16x16x32_bf16.
__global__ __launch_bounds__(64) void kgram(
    const short* __restrict__ ai_bf, const short* __restrict__ aj_bf,
    const short* __restrict__ h_bf,
    float* __restrict__ ga, float* __restrict__ gh)
{
    int bid = blockIdx.x;
    int g = bid & 1;
    int s = (bid >> 1) & 15;
    int b = bid >> 5;
    const short* XA = (g ? h_bf : ai_bf) + b*256*64;
    const short* XB = (g ? h_bf : aj_bf) + b*256*64;
    float* G = (g ? gh : ga) + (b*256 + s*16)*256;

    int l = threadIdx.x, lo = l & 15, hi = l >> 4;

    bf16x8 a0 = *(const bf16x8*)&XA[(s*16 + lo)*64 + hi*8];
    bf16x8 a1 = *(const bf16x8*)&XA[(s*16 + lo)*64 + 32 + hi*8];

    #pragma unroll 4
    for (int jt = 0; jt < 16; ++jt) {
        bf16x8 b0 = *(const bf16x8*)&XB[(jt*16 + lo)*64 + hi*8];
        bf16x8 b1 = *(const bf16x8*)&XB[(jt*16 + lo)*64 + 32 + hi*8];
        f32x4 c = {0.f, 0.f, 0.f, 0.f};
        c = __builtin_amdgcn_mfma_f32_16x16x32_bf16(a0, b0, c, 0, 0, 0);
        c = __builtin_amdgcn_mfma_f32_16x16x32_bf16(a1, b1, c, 0, 0, 0);
        #pragma unroll
        for (int r = 0; r < 4; ++r)
            G[(hi*4 + r)*256 + jt*16 + lo] = c[r];
    }
}

// K2: chunked pair kernel. 4096 blocks x 256 threads.
// block = (4-i tile, 64-j chunk); thread = ONE pair (i, jl).
// stats from scalars+grams; pass2 LN->relu->dot(w2) (1 global b32 + 1 LDS b128 + 5 VALU per d);
// adj; float4 aggregation over the chunk -> hagg4[ch].
__global__ __launch_bounds__(256) void k2_pair(
    const float* __restrict__ a_i, const float* __restrict__ a_jT,
    const float* __restrict__ h,
    const float* __restrict__ ga_m, const float* __restrict__ gh_m,
    const float* __restrict__ sa_i, const float* __restrict__ qa_i,
    const float* __restrict__ sa_j, const float* __restrict__ qa_j,
    const float* __restrict__ sqh,
    const float* __restrict__ ln_g, const float* __restrict__ ln_b,
    const float* __restrict__ s_w2, const float* __restrict__ s_b2,
    float* __restrict__ hagg4)
{
    int blk  = blockIdx.x;
    int tile = blk >> 2, ch = blk & 3;
    int bi0  = tile * 4, b = bi0 >> 8;
    int j0   = ch * 64;
    int t    = threadIdx.x;
    int i    = t >> 6, jl = t & 63;
    int jg   = j0 + jl;
    int gj   = b*256 + jg;

    __shared__ float4 ibw[4][64];        // {a_i[i][d], ln_g[d], ln_b[d], s_w2[d]}
    __shared__ float  sai_s[4], qai_s[4], sqi_s[4];
    __shared__ float  adj_sh[4][64];     // [i][jl]
    __shared__ float4 part4[4][4][16];   // [i][jsub][dq]

    ibw[i][jl] = make_float4(a_i[(bi0+i)*64 + jl], ln_g[jl], ln_b[jl], s_w2[jl]);
    if (t < 4) {
        sai_s[t] = sa_i[bi0+t]; qai_s[t] = qa_i[bi0+t]; sqi_s[t] = sqh[bi0+t];
    }
    float saj = sa_j[gj], qaj = qa_j[gj], sqj = sqh[gj];
    float gav = ga_m[(bi0+i)*256 + jg];          // coalesced
    float ghv = gh_m[(bi0+i)*256 + jg];
    float b2  = s_b2[0];
    __syncthreads();

    // ---- LN stats from scalar decomposition ----
    float mu  = (sai_s[i] + saj) * (1.f/64.f);
    float pss = qai_s[i] + qaj + 2.f*gav;
    float var = pss * (1.f/64.f) - mu*mu;
    float rs  = rsqrtf(var + 1e-5f);
    float nr  = -mu * rs;
    float d2  = fmaxf(sqi_s[i] + sqj - 2.f*ghv, 0.f);

    // ---- pass 2: LN -> relu -> dot(w2); one pair per thread ----
    const float* ajb = a_jT + b*64*256 + j0;     // ajb[d*256 + jl]
    float acc = 0.f;
    #pragma unroll 16
    for (int d = 0; d < 64; ++d) {
        float  ajd = ajb[d*256 + jl];            // coalesced, L1-hot chunk
        float4 B   = ibw[i][d];                  // LDS b128 broadcast
        float pre = B.x + ajd;
        float v   = fmaf(pre, rs, nr);
        float tt  = fmaf(v, B.y, B.z);
        tt = fmaxf(tt, 0.f);
        acc = fmaf(tt, B.w, acc);
    }

    // ---- sigma, adj ----
    {
        float sp  = acc + b2;
        float sig = fmaxf(sp, 0.f) + log1pf(expf(-fabsf(sp)));   // softplus
        adj_sh[i][jl] = expf(-d2 / (2.f*sig*sig + 1e-6f));
    }
    __syncthreads();

    // ---- aggregation over this chunk: thread = (i2, jsub, dq) ----
    {
        int i2 = t >> 6, jsub = (t >> 4) & 3, dq = t & 15;
        const float* hb = h + (b*256 + j0)*64;
        float4 p = {0.f,0.f,0.f,0.f};
        #pragma unroll
        for (int k = 0; k < 16; ++k) {
            int jj = jsub*16 + k;
            float a = adj_sh[i2][jj];                       // wave-uniform-ish broadcast
            float4 hv = *(const float4*)&hb[jj*64 + dq*4];  // dense 256B rows, L1-shared
            p.x = fmaf(a, hv.x, p.x);
            p.y = fmaf(a, hv.y, p.y);
            p.z = fmaf(a, hv.z, p.z);
            p.w = fmaf(a, hv.w, p.w);
        }
        part4[i2][jsub][dq] = p;
    }
    __syncthreads();

    if (t < 64) {
        int i2 = t >> 4, dq = t & 15;
        float4 p0 = part4[i2][0][dq], p1 = part4[i2][1][dq];
        float4 p2 = part4[i2][2][dq], p3 = part4[i2][3][dq];
        float4 s;
        s.x = p0.x + p1.x + p2.x + p3.x;
        s.y = p0.y + p1.y + p2.y + p3.y;
        s.z = p0.z + p1.z + p2.z + p3.z;
        s.w = p0.w + p1.w + p2.w + p3.w;
        *(float4*)&hagg4[((size_t)ch*262144) + (size_t)(bi0 + i2)*64 + dq*4] = s;
    }
}

// K3: h_res = elu((sum_ch hagg4) @ gnn_w + h).  1024 blocks x 256 thr.
__global__ __launch_bounds__(256) void k3_gnn(
    const float* __restrict__ hagg4, const float* __restrict__ h,
    const float* __restrict__ gnn_w, float* __restrict__ h_res)
{
    int lane = threadIdx.x & 63, wave = threadIdx.x >> 6;
    int row = blockIdx.x*4 + wave;
    __shared__ float agg_sh[4][64];
    agg_sh[wave][lane] = hagg4[row*64 + lane]
                       + hagg4[262144 + row*64 + lane]
                       + hagg4[524288 + row*64 + lane]
                       + hagg4[786432 + row*64 + lane];
    __syncthreads();
    float acc = 0.f;
    #pragma unroll 8
    for (int e = 0; e < 64; ++e)
        acc = fmaf(agg_sh[wave][e], gnn_w[e*64 + lane], acc);
    h_res[row*64 + lane] = elu_f(acc + h[row*64 + lane]);
}

// K4: pooled = [mean_i, max_i]; classifier.  16 blocks x 256 threads.
__global__ __launch_bounds__(256) void k4_pool_cls(
    const float* __restrict__ h_res,
    const float* __restrict__ c_w1, const float* __restrict__ c_b1,
    const float* __restrict__ bn_g, const float* __restrict__ bn_b,
    const float* __restrict__ bn_mean, const float* __restrict__ bn_var,
    const float* __restrict__ c_w2, const float* __restrict__ c_b2,
    float* __restrict__ out)
{
    int b = blockIdx.x;
    int tid = threadIdx.x;
    int d = tid & 63, q = tid >> 6;
    const float* hb = h_res + b*256*64;

    float sum = 0.f, mx = -INFINITY;
    #pragma unroll 8
    for (int k = 0; k < 64; ++k) {
        float v = hb[(q*64+k)*64 + d];
        sum += v; mx = fmaxf(mx, v);
    }
    __shared__ float sum_sh[256], max_sh[256];
    __shared__ float pm_sh[64], px_sh[64];
    sum_sh[tid] = sum; max_sh[tid] = mx;
    __syncthreads();
    if (tid < 64) {
        float tsum = sum_sh[tid] + sum_sh[64+tid] + sum_sh[128+tid] + sum_sh[192+tid];
        float tmax = fmaxf(fmaxf(max_sh[tid], max_sh[64+tid]),
                           fmaxf(max_sh[128+tid], max_sh[192+tid]));
        pm_sh[tid] = tsum * (1.f/256.f);
        px_sh[tid] = tmax;
    }
    __syncthreads();
    if (tid < 64) {
        float acc = c_b1[tid];
        #pragma unroll
        for (int e = 0; e < 64; ++e) {
            acc += pm_sh[e] * c_w1[e*64 + tid];
            acc += px_sh[e] * c_w1[(64+e)*64 + tid];
        }
        float z = (acc - bn_mean[tid]) * rsqrtf(bn_var[tid] + 1e-5f) * bn_g[tid] + bn_b[tid];
        z = elu_f(z);
        float c0 = z * c_w2[tid*2 + 0];
        float c1 = z * c_w2[tid*2 + 1];
        for (int off = 32; off > 0; off >>= 1) {
            c0 += __shfl_down(c0, off);
            c1 += __shfl_down(c1, off);
        }
        if (tid == 0) {
            out[b*2 + 0] = c0 + c_b2[0];
            out[b*2 + 1] = c1 + c_b2[1];
        }
    }
}

extern "C" void kernel_launch(void* const* d_in, const int* in_sizes, int n_in,
                              void* d_out, int out_size, void* d_ws, size_t ws_size,
                              hipStream_t stream) {
    const float* x       = (const float*)d_in[0];
    const float* proj_w  = (const float*)d_in[1];
    const float* proj_b  = (const float*)d_in[2];
    const float* s_w1    = (const float*)d_in[3];
    const float* s_b1    = (const float*)d_in[4];
    const float* ln_g    = (const float*)d_in[5];
    const float* ln_b    = (const float*)d_in[6];
    const float* s_w2    = (const float*)d_in[7];
    const float* s_b2    = (const float*)d_in[8];
    const float* gnn_w   = (const float*)d_in[9];
    const float* c_w1    = (const float*)d_in[10];
    const float* c_b1    = (const float*)d_in[11];
    const float* bn_g    = (const float*)d_in[12];
    const float* bn_b    = (const float*)d_in[13];
    const float* bn_mean = (const float*)d_in[14];
    const float* bn_var  = (const float*)d_in[15];
    const float* c_w2    = (const float*)d_in[16];
    const float* c_b2    = (const float*)d_in[17];

    float* w = (float*)d_ws;
    float* h     = w + OFF_H;
    float* a_i   = w + OFF_AI;
    float* a_jT  = w + OFF_AJT;
    float* sa_i  = w + OFF_SAI;
    float* qa_i  = w + OFF_QAI;
    float* sa_j  = w + OFF_SAJ;
    float* qa_j  = w + OFF_QAJ;
    float* sqh   = w + OFF_SQH;
    float* ga    = w + OFF_GA;
    float* gh    = w + OFF_GH;
    float* hagg4 = w + OFF_HAGG4;
    float* h_res = w + OFF_HRES;
    short* ai_bf = (short*)(w + OFF_BF);
    short* aj_bf = ai_bf + 262144;
    short* h_bf  = ai_bf + 524288;
    float* out   = (float*)d_out;

    k1_embed<<<512, 256, 0, stream>>>(x, proj_w, proj_b, s_w1, s_b1,
                                      h, a_i, a_jT, ai_bf, aj_bf, h_bf,
                                      sa_i, qa_i, sa_j, qa_j, sqh);
    kgram<<<512, 64, 0, stream>>>(ai_bf, aj_bf, h_bf, ga, gh);
    k2_pair<<<4096, 256, 0, stream>>>(a_i, a_jT, h, ga, gh,
                                      sa_i, qa_i, sa_j, qa_j, sqh,
                                      ln_g, ln_b, s_w2, s_b2, hagg4);
    k3_gnn<<<1024, 256, 0, stream>>>(hagg4, h, gnn_w, h_res);
    k4_pool_cls<<<16, 256, 0, stream>>>(h_res, c_w1, c_b1, bn_g, bn_b,
                                        bn_mean, bn_var, c_w2, c_b2, out);
}